// Round 4
// baseline (787.175 us; speedup 1.0000x reference)
//
#include <hip/hip_runtime.h>
#include <hip/hip_bf16.h>
#include <stdint.h>
#include <stddef.h>

typedef __hip_bfloat16 bf16;
typedef __attribute__((ext_vector_type(8))) __bf16 bf16x8;
typedef __attribute__((ext_vector_type(4))) float f32x4;

__device__ __forceinline__ bf16 f2b(float x) { return __float2bfloat16(x); }

// ---------------------------------------------------------------- utility kernels
__global__ void zero_kernel(float* __restrict__ p, int n) {
    int i = blockIdx.x * blockDim.x + threadIdx.x;
    if (i < n) p[i] = 0.f;
}

// WT[n*Kpad + k] = bf16( (k < K) ? W[k*N + n] : 0 )   (W is fp32)
__global__ void transpose_pad_kernel(const float* __restrict__ W, bf16* __restrict__ WT,
                                     int K, int N, int Kpad) {
    int idx = blockIdx.x * blockDim.x + threadIdx.x;
    if (idx >= N * Kpad) return;
    int n = idx / Kpad;
    int k = idx - n * Kpad;
    WT[idx] = f2b((k < K) ? W[(size_t)k * N + n] : 0.f);
}

// one thread per (structure, triplet): emit 30 bf16 features; t==0 zeroes pad cols 300..319
__global__ void feat_kernel(const float* __restrict__ S, const float* __restrict__ E,
                            bf16* __restrict__ feat, int total) {
    int idx = blockIdx.x * blockDim.x + threadIdx.x;
    if (idx >= total) return;
    int b = idx / 10;
    int t = idx - b * 10;
    const float* s = S + (size_t)idx * 3;
    float fi = s[0];
    float fj = s[1];
    float d  = s[2];
    int ii = (int)fi;   // indices stored as exact float32
    int jj = (int)fj;
    bf16* o = feat + (size_t)b * 320 + t * 30;
    const float* Ei = E + ii * 10;
    const float* Ej = E + jj * 10;
    #pragma unroll
    for (int c = 0; c < 10; ++c) o[c]      = f2b((ii != 0) ? Ei[c] : 0.f);
    #pragma unroll
    for (int c = 0; c < 10; ++c) o[10 + c] = f2b((jj != 0) ? Ej[c] : 0.f);
    #pragma unroll
    for (int c = 0; c < 10; ++c) {
        float df = (float)(c + 1) * 0.7f - d;
        float r  = (ii != 0) ? __expf(-df * df) : 0.f;   // GAMMA = 1
        o[20 + c] = f2b(r);
    }
    if (t == 0) {
        bf16* z = feat + (size_t)b * 320 + 300;
        #pragma unroll
        for (int c = 0; c < 20; ++c) z[c] = f2b(0.f);
    }
}

// ---------------------------------------------------------------- MFMA GEMM (m93-style staging)
// C[M,N] = A[M,K] @ BT[N,K]^T ; 128x128 tile, BK=64, 4 waves (2x2), 4x4 16x16x32 frags/wave.
// Staging: bf16x8 global loads -> registers -> ds_write_b128.
// EPI==0: C = relu(acc + bias) stored bf16.
// EPI==1: outf[row] += sum_col relu(acc+bias[col]) * w3[col]  (atomicAdd fp32)
template <int EPI>
__global__ __launch_bounds__(256)
void gemm_kernel(const bf16* __restrict__ A, const bf16* __restrict__ BT,
                 const float* __restrict__ bias, bf16* __restrict__ C,
                 float* __restrict__ outf, const float* __restrict__ w3,
                 int K, int lda, int ldbt, int ldc) {
    __shared__ bf16 sA[128 * 64];
    __shared__ bf16 sB[128 * 64];
    const int tid  = threadIdx.x;
    const int lane = tid & 63;
    const int wave = tid >> 6;
    const int wr = wave >> 1, wc = wave & 1;
    const int l16 = lane & 15, quad = lane >> 4;
    const size_t m0 = (size_t)blockIdx.x * 128;
    const int    n0 = blockIdx.y * 128;

    f32x4 acc[4][4];
    #pragma unroll
    for (int i = 0; i < 4; ++i)
        #pragma unroll
        for (int j = 0; j < 4; ++j) acc[i][j] = (f32x4){0.f, 0.f, 0.f, 0.f};

    for (int kk = 0; kk < K; kk += 64) {
        bf16x8 va[4], vb[4];
        #pragma unroll
        for (int i = 0; i < 4; ++i) {
            int s   = i * 256 + tid;       // segment 0..1023
            int row = s >> 3;              // 0..127
            int kof = (s & 7) << 3;        // 0,8,...,56 (bf16 elems)
            va[i] = *(const bf16x8*)(A  + (m0 + row) * lda          + kk + kof);
            vb[i] = *(const bf16x8*)(BT + (size_t)(n0 + row) * ldbt + kk + kof);
        }
        #pragma unroll
        for (int i = 0; i < 4; ++i) {
            int s = i * 256 + tid;
            *(bf16x8*)&sA[s * 8] = va[i];
            *(bf16x8*)&sB[s * 8] = vb[i];
        }
        __syncthreads();
        #pragma unroll
        for (int s2 = 0; s2 < 2; ++s2) {   // two k=32 MFMA steps per BK=64
            int ko = s2 * 32 + quad * 8;
            bf16x8 a[4], b[4];
            #pragma unroll
            for (int mi = 0; mi < 4; ++mi)
                a[mi] = *(const bf16x8*)&sA[(wr * 64 + mi * 16 + l16) * 64 + ko];
            #pragma unroll
            for (int ni = 0; ni < 4; ++ni)
                b[ni] = *(const bf16x8*)&sB[(wc * 64 + ni * 16 + l16) * 64 + ko];
            #pragma unroll
            for (int mi = 0; mi < 4; ++mi)
                #pragma unroll
                for (int ni = 0; ni < 4; ++ni)
                    acc[mi][ni] = __builtin_amdgcn_mfma_f32_16x16x32_bf16(
                        a[mi], b[ni], acc[mi][ni], 0, 0, 0);
        }
        __syncthreads();
    }

    if (EPI == 0) {
        #pragma unroll
        for (int mi = 0; mi < 4; ++mi) {
            #pragma unroll
            for (int ni = 0; ni < 4; ++ni) {
                int col = n0 + wc * 64 + ni * 16 + l16;
                float bv = bias[col];
                #pragma unroll
                for (int r = 0; r < 4; ++r) {
                    size_t row = m0 + wr * 64 + mi * 16 + quad * 4 + r;
                    float v = acc[mi][ni][r] + bv;
                    v = v > 0.f ? v : 0.f;
                    C[row * ldc + col] = f2b(v);
                }
            }
        }
    } else {
        #pragma unroll
        for (int mi = 0; mi < 4; ++mi) {
            #pragma unroll
            for (int r = 0; r < 4; ++r) {
                float p = 0.f;
                #pragma unroll
                for (int ni = 0; ni < 4; ++ni) {
                    int col = n0 + wc * 64 + ni * 16 + l16;
                    float v = acc[mi][ni][r] + bias[col];
                    v = v > 0.f ? v : 0.f;
                    p += v * w3[col];
                }
                // reduce across the 16 lanes sharing this row
                #pragma unroll
                for (int off = 1; off < 16; off <<= 1)
                    p += __shfl_xor(p, off, 64);
                if (l16 == 0) {
                    size_t row = m0 + wr * 64 + mi * 16 + quad * 4 + r;
                    atomicAdd(&outf[row], p);
                }
            }
        }
    }
}

__global__ void final_kernel(const float* __restrict__ outf, const float* __restrict__ b3,
                             float* __restrict__ out, int n) {
    int i = blockIdx.x * blockDim.x + threadIdx.x;
    if (i < n) out[i] = outf[i] + b3[0];
}

// ---------------------------------------------------------------- zero-workspace fallback
// 8 rows/block, fp32 throughout, feat+X1 in LDS. Slow but needs no d_ws.
#define FB_ROWS 8
__global__ __launch_bounds__(256)
void fallback_kernel(const float* __restrict__ S, const float* __restrict__ E,
                     const float* __restrict__ W1, const float* __restrict__ b1,
                     const float* __restrict__ W2, const float* __restrict__ b2,
                     const float* __restrict__ W3, const float* __restrict__ b3,
                     float* __restrict__ out) {
    __shared__ float feat[FB_ROWS][304];
    __shared__ float X1[FB_ROWS][1024];
    __shared__ float red[256];
    const int tid = threadIdx.x;
    const size_t r0 = (size_t)blockIdx.x * FB_ROWS;

    if (tid < FB_ROWS * 10) {
        int r = tid / 10, t = tid - r * 10;
        const float* s = S + (r0 + r) * 30 + t * 3;
        float fi = s[0], fj = s[1], d = s[2];
        int ii = (int)fi;
        int jj = (int)fj;
        float* o = &feat[r][t * 30];
        #pragma unroll
        for (int c = 0; c < 10; ++c) o[c]      = (ii != 0) ? E[ii * 10 + c] : 0.f;
        #pragma unroll
        for (int c = 0; c < 10; ++c) o[10 + c] = (jj != 0) ? E[jj * 10 + c] : 0.f;
        #pragma unroll
        for (int c = 0; c < 10; ++c) {
            float df = (float)(c + 1) * 0.7f - d;
            o[20 + c] = (ii != 0) ? __expf(-df * df) : 0.f;
        }
    }
    __syncthreads();

    for (int i = 0; i < FB_ROWS * 1024 / 256; ++i) {
        int idx = i * 256 + tid;
        int r = idx & (FB_ROWS - 1);
        int c = idx >> 3;               // FB_ROWS == 8
        float a = b1[c];
        for (int k = 0; k < 300; ++k)
            a += feat[r][k] * W1[(size_t)k * 1024 + c];
        X1[r][c] = a > 0.f ? a : 0.f;
    }
    __syncthreads();

    {
        int r  = tid & (FB_ROWS - 1);
        int cg = tid >> 3;              // 32 col groups of 32
        float acc = 0.f;
        for (int cc = 0; cc < 32; ++cc) {
            int c = cg * 32 + cc;
            float a = b2[c];
            for (int k = 0; k < 1024; ++k)
                a += X1[r][k] * W2[(size_t)k * 1024 + c];
            a = a > 0.f ? a : 0.f;
            acc += a * W3[c];
        }
        red[tid] = acc;
    }
    __syncthreads();
    if (tid < FB_ROWS) {
        float s = 0.f;
        for (int g = 0; g < 32; ++g) s += red[g * FB_ROWS + tid];
        out[r0 + tid] = s + b3[0];
    }
}

// ---------------------------------------------------------------- launch
extern "C" void kernel_launch(void* const* d_in, const int* in_sizes, int n_in,
                              void* d_out, int out_size, void* d_ws, size_t ws_size,
                              hipStream_t stream) {
    const float* S  = (const float*)d_in[0];   // [B,T,3] fp32
    const float* E  = (const float*)d_in[1];   // [118,10] fp32
    const float* W1 = (const float*)d_in[2];   // [300,1024] fp32
    const float* b1 = (const float*)d_in[3];   // [1024] fp32
    const float* W2 = (const float*)d_in[4];   // [1024,1024] fp32
    const float* b2 = (const float*)d_in[5];   // [1024] fp32
    const float* W3 = (const float*)d_in[6];   // [1024,1] fp32
    const float* b3 = (const float*)d_in[7];   // [1] fp32
    float* out = (float*)d_out;

    const int Bn  = out_size;   // 131072
    const int HID = 1024;
    const int K1  = 320;        // 300 padded to multiple of 64

    const size_t MIN_WS = 4u * 1024u * 1024u;
    if (ws_size < MIN_WS) {
        fallback_kernel<<<Bn / FB_ROWS, 256, 0, stream>>>(S, E, W1, b1, W2, b2, W3, b3, out);
        return;
    }

    char* ws = (char*)d_ws;
    size_t off = 0;
    auto take = [&](size_t bytes) { char* p = ws + off; off += (bytes + 255) & ~(size_t)255; return p; };
    float* outf = (float*)take((size_t)Bn * sizeof(float));
    bf16*  W1T  = (bf16*) take((size_t)HID * K1 * sizeof(bf16));
    bf16*  W2T  = (bf16*) take((size_t)HID * HID * sizeof(bf16));

    size_t avail   = ws_size - off - 256;
    size_t per_row = (size_t)K1 * sizeof(bf16) + (size_t)HID * sizeof(bf16); // 2688 B
    size_t chunk   = (avail / per_row) & ~(size_t)127;   // multiple of 128 rows
    if (chunk > (size_t)Bn) chunk = Bn;
    bf16* featc = (bf16*)take(chunk * K1 * sizeof(bf16));
    bf16* X1c   = (bf16*)take(chunk * HID * sizeof(bf16));

    zero_kernel<<<(Bn + 255) / 256, 256, 0, stream>>>(outf, Bn);
    transpose_pad_kernel<<<(HID * K1 + 255) / 256, 256, 0, stream>>>(W1, W1T, 300, HID, K1);
    transpose_pad_kernel<<<(HID * HID + 255) / 256, 256, 0, stream>>>(W2, W2T, HID, HID, HID);

    for (size_t r0 = 0; r0 < (size_t)Bn; r0 += chunk) {
        size_t rows = ((size_t)Bn - r0 < chunk) ? ((size_t)Bn - r0) : chunk;
        int nt = (int)(rows * 10);
        feat_kernel<<<(nt + 255) / 256, 256, 0, stream>>>(S + r0 * 30, E, featc, nt);
        dim3 grid((unsigned)(rows / 128), HID / 128);
        gemm_kernel<0><<<grid, 256, 0, stream>>>(featc, W1T, b1, X1c, nullptr, nullptr,
                                                 K1, K1, K1, HID);
        gemm_kernel<1><<<grid, 256, 0, stream>>>(X1c, W2T, b2, nullptr, outf + r0, W3,
                                                 HID, HID, HID, 0);
    }
    final_kernel<<<(Bn + 255) / 256, 256, 0, stream>>>(outf, b3, out, Bn);
}